// Round 2
// 236.733 us; speedup vs baseline: 1.0072x; 1.0072x over previous
//
#include <hip/hip_runtime.h>

// Problem constants (fixed by the reference).
#define BB 4
#define SS 4096
#define DD 2048
#define KK 4
#define D4 (DD / 4)        // 512 float4 channel-groups
#define CHUNK 16           // s-steps per thread
#define NCH (SS / CHUNK)   // 256 chunks per (b, column)
#define G 4                // s-positions per group (independent-load batch)
#define NG (CHUNK / G)     // 4 groups per thread

// Native clang vector type: __builtin_nontemporal_store requires it
// (HIP_vector_type<float,4> is a struct and is rejected).
typedef float f32x4 __attribute__((ext_vector_type(4)));

// y[b,s,d] = bias[d] + sum_{k=0..3} x[b, s-3+k, d] * W[d,k]   (zero-pad s<0)
//
// v2: latency fix. v1 compiled to a 1-load-in-flight chain
// (VGPR=36, load -> vmcnt(0) -> fma -> store per s-step; VALUBusy 3.4%,
// HBM 32% of peak => memory-LATENCY bound, not BW bound).
// Each thread processes s in groups of 4 with the NEXT group's 4
// independent loads issued before the current group's FMAs+stores
// (double-buffered registers => 4-8 loads in flight per wave).
// Stores are nontemporal: y is never re-read, keep it from evicting x
// (134 MB, fits in 256 MB Infinity Cache) out of L2/L3.

__device__ __forceinline__ float4 conv4(const float4 bv,
                                        const float4 wr0, const float4 wr1,
                                        const float4 wr2, const float4 wr3,
                                        const float4 xm3, const float4 xm2,
                                        const float4 xm1, const float4 xc) {
  // lane component j (d = 4*d4+j) uses weight row wrj = {W[d,0..3]}
  float4 r;
  r.x = bv.x + wr0.x * xm3.x + wr0.y * xm2.x + wr0.z * xm1.x + wr0.w * xc.x;
  r.y = bv.y + wr1.x * xm3.y + wr1.y * xm2.y + wr1.z * xm1.y + wr1.w * xc.y;
  r.z = bv.z + wr2.x * xm3.z + wr2.y * xm2.z + wr2.z * xm1.z + wr2.w * xc.z;
  r.w = bv.w + wr3.x * xm3.w + wr3.y * xm2.w + wr3.z * xm1.w + wr3.w * xc.w;
  return r;
}

__device__ __forceinline__ void nt_store4(float4* p, const float4 v) {
  f32x4 tmp;
  tmp.x = v.x; tmp.y = v.y; tmp.z = v.z; tmp.w = v.w;
  __builtin_nontemporal_store(tmp, (f32x4*)p);
}

__global__ __launch_bounds__(256) void shortconv_kernel(
    const float4* __restrict__ x,      // (B,S,D) as float4 over D
    const float4* __restrict__ w4,     // (D,4): w4[d] = {W[d,0],W[d,1],W[d,2],W[d,3]}
    const float4* __restrict__ bias4,  // (D/4)
    float4* __restrict__ y)            // (B,S,D) as float4 over D
{
    const int t    = blockIdx.x * 256 + threadIdx.x;
    const int d4   = t & (D4 - 1);
    const int rest = t >> 9;            // / D4
    const int ch   = rest & (NCH - 1);
    const int b    = rest >> 8;         // / NCH

    const float4 wr0 = w4[4 * d4 + 0];
    const float4 wr1 = w4[4 * d4 + 1];
    const float4 wr2 = w4[4 * d4 + 2];
    const float4 wr3 = w4[4 * d4 + 3];
    const float4 bv  = bias4[d4];

    const int s0 = ch * CHUNK;
    const size_t base = ((size_t)b * SS + (size_t)s0) * D4 + (size_t)d4;

    // halo window: x[s0-3], x[s0-2], x[s0-1]  (block-uniform branch)
    float4 h0, h1, h2;
    if (ch == 0) {
        h0 = make_float4(0.f, 0.f, 0.f, 0.f);
        h1 = h0;
        h2 = h0;
    } else {
        h0 = x[base - 3 * (size_t)D4];
        h1 = x[base - 2 * (size_t)D4];
        h2 = x[base - 1 * (size_t)D4];
    }

    // current group: 4 independent loads
    float4 a0 = x[base + 0 * (size_t)D4];
    float4 a1 = x[base + 1 * (size_t)D4];
    float4 a2 = x[base + 2 * (size_t)D4];
    float4 a3 = x[base + 3 * (size_t)D4];

#pragma unroll
    for (int g = 0; g < NG; ++g) {
        // issue next group's 4 independent loads BEFORE computing/storing
        // the current group -> they fly during the FMAs and nt-stores
        float4 n0, n1, n2, n3;
        if (g + 1 < NG) {
            const size_t nb = base + (size_t)((g + 1) * G) * D4;
            n0 = x[nb + 0 * (size_t)D4];
            n1 = x[nb + 1 * (size_t)D4];
            n2 = x[nb + 2 * (size_t)D4];
            n3 = x[nb + 3 * (size_t)D4];
        }

        const size_t ob = base + (size_t)(g * G) * D4;
        const float4 r0 = conv4(bv, wr0, wr1, wr2, wr3, h0, h1, h2, a0);
        const float4 r1 = conv4(bv, wr0, wr1, wr2, wr3, h1, h2, a0, a1);
        const float4 r2 = conv4(bv, wr0, wr1, wr2, wr3, h2, a0, a1, a2);
        const float4 r3 = conv4(bv, wr0, wr1, wr2, wr3, a0, a1, a2, a3);

        nt_store4(&y[ob + 0 * (size_t)D4], r0);
        nt_store4(&y[ob + 1 * (size_t)D4], r1);
        nt_store4(&y[ob + 2 * (size_t)D4], r2);
        nt_store4(&y[ob + 3 * (size_t)D4], r3);

        if (g + 1 < NG) {
            h0 = a1; h1 = a2; h2 = a3;     // window = last 3 of current group
            a0 = n0; a1 = n1; a2 = n2; a3 = n3;
        }
    }
}

extern "C" void kernel_launch(void* const* d_in, const int* in_sizes, int n_in,
                              void* d_out, int out_size, void* d_ws, size_t ws_size,
                              hipStream_t stream) {
    const float* x    = (const float*)d_in[0];  // (B,S,D) fp32
    const float* w    = (const float*)d_in[1];  // (D,1,K) fp32
    const float* bias = (const float*)d_in[2];  // (D,)   fp32
    float* out        = (float*)d_out;          // (B,S,D) fp32

    const int total_threads = BB * NCH * D4;    // 524288 = 8192 waves (fills 256 CUs)
    const int block = 256;
    const int grid  = total_threads / block;    // 2048

    shortconv_kernel<<<grid, block, 0, stream>>>(
        (const float4*)x, (const float4*)w, (const float4*)bias, (float4*)out);
}